// Round 16
// baseline (104.052 us; speedup 1.0000x reference)
//
#include <hip/hip_runtime.h>
#include <hip/hip_bf16.h>

typedef __bf16 bf16x8 __attribute__((ext_vector_type(8)));
typedef float  f32x4  __attribute__((ext_vector_type(4)));

#define VOCAB 24
#define EDIM  16
#define HDIM  32
#define TLEN  128

union A2U { int4 w; bf16x8 v; };

__device__ __forceinline__ float ex2(float x)  { return __builtin_amdgcn_exp2f(x); }
__device__ __forceinline__ float rcpf_(float x){ return __builtin_amdgcn_rcpf(x); }

// EXCHANGE-FREE wave-private design: block = 1 wave = 16 batch rows.
// Swapped-operand MFMA (R10-verified): gates^T = mfma(A=W-frags, B=h^T /
// onehot^T), D[m=gatecol][n=row]. Gate columns PERMUTED so the C-layout
// hands each lane exactly the h values its own next-step B-fragment needs:
//   tile nt: gate g = nt>>1 (0=i,1=f,2=g,3=o);
//   column m -> hidden j = 8*(m>>2) + (m&3) + 4*(nt&1).
// Lane (l15,hi) reads D[m=4hi+r][n=l15] -> gate g of hidden j=8hi+r+4*(nt&1)
// of batch row l15; element k (j=8hi+k, qq=k>>2, r=k&3): i=acc[qq],
// f=acc[2+qq], g=acc[4+qq], o=acc[6+qq]. After the update the lane holds
// h[l15][8hi..8hi+7] — exactly its own B-frag slice B[k=8hi+i][n=l15] for the
// next step. h-"exchange" = 8 bf16 casts in-register. No LDS / DS ops / sync
// in the recurrence.
// vs R14 (NaN): hb built with plain (__bf16) casts (no inline-asm cvtpk into
// a union — the untested pattern), PRECOMP back at R13's end-of-slot position,
// and dd clamped at +80 (exact tanh saturation; inert on correct data, makes
// any residual wiring error show as finite absmax instead of NaN).
// Activations (R12/R13-verified): B pre-scaled by -log2e (i,f,o) / -2log2e
// (g); ea,ew,eb,ev = exp2(accs); P=(1+ea)(1+eb); T=(1+ew);
// d' = fmaf(d,P,fmaf(2.885,eb,-2.885)*T)*rcp(T*P); eu=exp2(d');
// h = (1-eu)*rcp((1+ev)(1+eu)).
__global__ __launch_bounds__(64) void lstm_fused(
    const int*   __restrict__ x,     // [B][128]
    const float* __restrict__ emb,   // [24][16]
    const float* __restrict__ W_ih,  // [128][16]
    const float* __restrict__ W_hh,  // [128][32]
    const float* __restrict__ b_ih,  // [128]
    const float* __restrict__ b_hh,  // [128]
    const float* __restrict__ fc_w,  // [2][32]
    const float* __restrict__ fc_b,  // [2]
    float*       __restrict__ out)   // [B][2]
{
    __shared__ __align__(16) float fbuf[16][33];   // final h (f32), FC only

    const int lane  = threadIdx.x;       // 0..63
    const int l15   = lane & 15;
    const int hi    = lane >> 4;         // 0..3
    const int kbase = hi * 8;
    const int kh    = hi * 4;            // packed-word index base
    const int row0  = blockIdx.x * 16;

    // ---- A-fragments (permuted gate columns), pre-scaled, registers ----
    // A[m=l15][k=kbase+i] per tile nt; gcol = g*32 + jcol(m=l15, nt).
    bf16x8 b1f[8];  // scale * W_hh
    bf16x8 b2f[8];  // scale * (emb[v].W_ih[gcol] + b_ih + b_hh), k = vocab v
    #pragma unroll
    for (int nt = 0; nt < 8; ++nt) {
        const int g    = nt >> 1;
        const int jcol = 8 * (l15 >> 2) + (l15 & 3) + 4 * (nt & 1);
        const int gcol = g * 32 + jcol;
        const float scale = (g == 2) ? -2.88539008f : -1.44269504f;
        const float* wrow = W_hh + gcol * HDIM;
        #pragma unroll
        for (int i = 0; i < 8; ++i)
            b1f[nt][i] = (__bf16)(scale * wrow[kbase + i]);
        const float bias = b_ih[gcol] + b_hh[gcol];
        const float* wi = W_ih + gcol * EDIM;
        #pragma unroll
        for (int i = 0; i < 8; ++i) {
            const int v = kbase + i;
            float s = 0.0f;
            if (v < VOCAB) {
                s = bias;
                #pragma unroll
                for (int e = 0; e < EDIM; ++e)
                    s += emb[v * EDIM + e] * wi[e];
            }
            b2f[nt][i] = (__bf16)(scale * s);
        }
    }

    float d[8];                          // d = -2*log2e * c  (scaled domain)
    #pragma unroll
    for (int q = 0; q < 8; ++q) d[q] = 0.0f;

    f32x4 p[8];                          // pipelined gates_x accumulators
    bf16x8 hb;                           // h B-fragment (own values)
    #pragma unroll
    for (int i = 0; i < 8; ++i) hb[i] = (__bf16)0.0f;

    const f32x4 z = {0.f, 0.f, 0.f, 0.f};
    const int* xrow = x + (row0 + l15) * TLEN;   // tokens of batch row l15

// one-hot gates_x MFMAs for token XV -> p[]  (one-hot as B-operand, n=row)
#define PRECOMP(XV) do {                                                       \
    const int xv_   = (XV);                                                    \
    const int hotw_ = 0x3F80 << ((xv_ & 1) << 4);                              \
    const int hoth_ = xv_ >> 1;                                                \
    A2U a2_;                                                                   \
    a2_.w.x = (hoth_ == kh + 0) ? hotw_ : 0;                                   \
    a2_.w.y = (hoth_ == kh + 1) ? hotw_ : 0;                                   \
    a2_.w.z = (hoth_ == kh + 2) ? hotw_ : 0;                                   \
    a2_.w.w = (hoth_ == kh + 3) ? hotw_ : 0;                                   \
    _Pragma("unroll")                                                          \
    for (int nt = 0; nt < 8; ++nt)                                             \
        p[nt] = __builtin_amdgcn_mfma_f32_16x16x32_bf16(b2f[nt], a2_.v, z, 0, 0, 0); \
} while (0)

// One timestep. On entry p[] = this step's gates_x, hb = h fragment (t>0).
#define SLOT(FIRST, LAST, XVN) do {                                            \
    f32x4 acc_[8];                                                             \
    if (FIRST) {                                                               \
        _Pragma("unroll")                                                      \
        for (int nt = 0; nt < 8; ++nt) acc_[nt] = p[nt];                       \
    } else {                                                                   \
        _Pragma("unroll")                                                      \
        for (int nt = 0; nt < 8; ++nt)                                         \
            acc_[nt] = __builtin_amdgcn_mfma_f32_16x16x32_bf16(b1f[nt], hb, p[nt], 0, 0, 0); \
    }                                                                          \
    /* ---- SoA pass 1: 32 independent exp2 ---- */                            \
    float ea_[8], ew_[8], eb_[8], ev_[8];                                      \
    _Pragma("unroll")                                                          \
    for (int k = 0; k < 8; ++k) {                                              \
        const int qq_ = k >> 2, r_ = k & 3;                                    \
        ea_[k] = ex2(acc_[qq_    ][r_]);   /* i */                             \
        ew_[k] = ex2(acc_[qq_ + 2][r_]);   /* f */                             \
        eb_[k] = ex2(acc_[qq_ + 4][r_]);   /* g (2x scale) */                  \
        ev_[k] = ex2(acc_[qq_ + 6][r_]);   /* o */                             \
    }                                                                          \
    /* ---- SoA pass 2: dependent VALU / rcp / exp2, pack h ---- */            \
    _Pragma("unroll")                                                          \
    for (int k = 0; k < 8; ++k) {                                              \
        const float P_ = (1.0f + ea_[k]) * (1.0f + eb_[k]);                    \
        const float T_ = 1.0f + ew_[k];                                        \
        const float G_ = fmaf(2.88539008f, eb_[k], -2.88539008f);              \
        const float N_ = fmaf(d[k], P_, G_ * T_);                              \
        const float dd = fminf(N_ * rcpf_(T_ * P_), 80.0f);                    \
        d[k] = dd;                                                             \
        const float eu = ex2(dd);                                              \
        const float hv = (1.0f - eu) * rcpf_((1.0f + ev_[k]) * (1.0f + eu));   \
        if (!(LAST)) hb[k] = (__bf16)hv;    /* own B-frag slice, in-register */\
        else         fbuf[l15][kbase + k] = hv;                                \
    }                                                                          \
    if (!(LAST)) PRECOMP(XVN);   /* next-step gates_x (R13 position) */        \
} while (0)

    // ---- prologue: tokens 0-3 and 4-7; gates_x for t=0 ----
    int4 q0 = *(const int4*)xrow;
    int4 xq = *(const int4*)(xrow + 4);
    PRECOMP(q0.x);

    // t = 0..3
    SLOT(true,  false, q0.y);
    SLOT(false, false, q0.z);
    SLOT(false, false, q0.w);
    SLOT(false, false, xq.x);

    // main: t = 4..123, 4 steps/iter; tokens prefetched one iteration ahead
    #pragma unroll 1
    for (int t = 4; t < 124; t += 4) {
        const int4 n = *(const int4*)(xrow + t + 4);
        SLOT(false, false, xq.y);   // t
        SLOT(false, false, xq.z);   // t+1
        SLOT(false, false, xq.w);   // t+2
        SLOT(false, false, n.x);    // t+3
        xq = n;
    }

    // tail: t = 124..127
    SLOT(false, false, xq.y);       // 124
    SLOT(false, false, xq.z);       // 125
    SLOT(false, false, xq.w);       // 126
    SLOT(false, true,  0);          // 127 -> fbuf (f32)

#undef SLOT
#undef PRECOMP

    __syncthreads();   // single wave: drains fbuf writes before cross-lane read

    // ---- FC epilogue: out[b] = h_last[b] @ fc_w^T + fc_b ----
    if (lane < 16) {
        float o0 = fc_b[0], o1 = fc_b[1];
        #pragma unroll
        for (int jj = 0; jj < HDIM; ++jj) {
            const float h = fbuf[lane][jj];
            o0 += fc_w[jj]        * h;
            o1 += fc_w[HDIM + jj] * h;
        }
        float2 res;
        res.x = o0; res.y = o1;
        *(float2*)&out[(row0 + lane) * 2] = res;
    }
}

extern "C" void kernel_launch(void* const* d_in, const int* in_sizes, int n_in,
                              void* d_out, int out_size, void* d_ws, size_t ws_size,
                              hipStream_t stream) {
    const int*   x    = (const int*)  d_in[0];
    const float* emb  = (const float*)d_in[1];
    const float* W_ih = (const float*)d_in[2];
    const float* W_hh = (const float*)d_in[3];
    const float* b_ih = (const float*)d_in[4];
    const float* b_hh = (const float*)d_in[5];
    const float* fc_w = (const float*)d_in[6];
    const float* fc_b = (const float*)d_in[7];
    float* out = (float*)d_out;

    const int B    = in_sizes[0] / TLEN;   // 16384
    const int nblk = B / 16;               // 1024 waves, 1 per SIMD chip-wide

    lstm_fused<<<nblk, 64, 0, stream>>>(x, emb, W_ih, W_hh, b_ih, b_hh, fc_w, fc_b, out);
}

// Round 17
// 102.319 us; speedup vs baseline: 1.0169x; 1.0169x over previous
//
#include <hip/hip_runtime.h>
#include <hip/hip_bf16.h>

typedef __bf16 bf16x8 __attribute__((ext_vector_type(8)));
typedef float  f32x4  __attribute__((ext_vector_type(4)));

#define VOCAB 24
#define EDIM  16
#define HDIM  32
#define TLEN  128

union A2U { int4 w; bf16x8 v; };

__device__ __forceinline__ float ex2(float x)  { return __builtin_amdgcn_exp2f(x); }
__device__ __forceinline__ float rcpf_(float x){ return __builtin_amdgcn_rcpf(x); }

// EXCHANGE-FREE wave-private design (R15-verified): block = 1 wave = 16
// batch rows. Swapped-operand MFMA: gates^T = mfma(A=W-frags, B=h^T/onehot^T),
// D[m=gatecol][n=row]; gate columns permuted so each lane's C-slice IS its
// own next-step B-fragment:
//   tile nt: gate g = nt>>1; column m -> hidden j = 8*(m>>2)+(m&3)+4*(nt&1).
// Lane (l15,hi): element k (j=8hi+k): i=acc[k>>2], f=acc[2+(k>>2)],
// g=acc[4+(k>>2)], o=acc[6+(k>>2)], reg r=k&3. h-"exchange" = 8 bf16 casts.
// No LDS/DS/sync in the recurrence.
//
// R16 vs R15 (trans diet, 7 -> 6 trans/element — kernel is trans-throughput
// bound per the R15 ledger: 56 trans x ~32cyc ~= the whole step):
//   pairwise rcp fusion at both rcp sites:
//     x = rcp(TP0*TP1); dd_k = N_k*x*TP_other   (1 rcp per pair, was 2)
//     y = rcp(U0*U1);   hv_k = (1-eu_k)*y*U_other
//   dd clamped at +40 (exact: tanh saturated to 2^-40; bounds eu<=2^40 so
//   the pair product U0*U1 <= ~2^108 cannot overflow).
// Activations otherwise R12/R13-verified: B pre-scaled by -log2e (i,f,o) /
// -2log2e (g); ea,ew,eb,ev = exp2(accs); P=(1+ea)(1+eb); T=(1+ew);
// N = fmaf(d, P, fmaf(2.885,eb,-2.885)*T); d' = N/(T*P); eu=exp2(d');
// h = (1-eu)/((1+ev)(1+eu)).
__global__ __launch_bounds__(64) void lstm_fused(
    const int*   __restrict__ x,     // [B][128]
    const float* __restrict__ emb,   // [24][16]
    const float* __restrict__ W_ih,  // [128][16]
    const float* __restrict__ W_hh,  // [128][32]
    const float* __restrict__ b_ih,  // [128]
    const float* __restrict__ b_hh,  // [128]
    const float* __restrict__ fc_w,  // [2][32]
    const float* __restrict__ fc_b,  // [2]
    float*       __restrict__ out)   // [B][2]
{
    __shared__ __align__(16) float fbuf[16][33];   // final h (f32), FC only

    const int lane  = threadIdx.x;       // 0..63
    const int l15   = lane & 15;
    const int hi    = lane >> 4;         // 0..3
    const int kbase = hi * 8;
    const int kh    = hi * 4;            // packed-word index base
    const int row0  = blockIdx.x * 16;

    // ---- A-fragments (permuted gate columns), pre-scaled, registers ----
    bf16x8 b1f[8];  // scale * W_hh
    bf16x8 b2f[8];  // scale * (emb[v].W_ih[gcol] + b_ih + b_hh), k = vocab v
    #pragma unroll
    for (int nt = 0; nt < 8; ++nt) {
        const int g    = nt >> 1;
        const int jcol = 8 * (l15 >> 2) + (l15 & 3) + 4 * (nt & 1);
        const int gcol = g * 32 + jcol;
        const float scale = (g == 2) ? -2.88539008f : -1.44269504f;
        const float* wrow = W_hh + gcol * HDIM;
        #pragma unroll
        for (int i = 0; i < 8; ++i)
            b1f[nt][i] = (__bf16)(scale * wrow[kbase + i]);
        const float bias = b_ih[gcol] + b_hh[gcol];
        const float* wi = W_ih + gcol * EDIM;
        #pragma unroll
        for (int i = 0; i < 8; ++i) {
            const int v = kbase + i;
            float s = 0.0f;
            if (v < VOCAB) {
                s = bias;
                #pragma unroll
                for (int e = 0; e < EDIM; ++e)
                    s += emb[v * EDIM + e] * wi[e];
            }
            b2f[nt][i] = (__bf16)(scale * s);
        }
    }

    float d[8];                          // d = -2*log2e * c  (scaled domain)
    #pragma unroll
    for (int q = 0; q < 8; ++q) d[q] = 0.0f;

    f32x4 p[8];                          // pipelined gates_x accumulators
    bf16x8 hb;                           // h B-fragment (own values)
    #pragma unroll
    for (int i = 0; i < 8; ++i) hb[i] = (__bf16)0.0f;

    const f32x4 z = {0.f, 0.f, 0.f, 0.f};
    const int* xrow = x + (row0 + l15) * TLEN;   // tokens of batch row l15

// one-hot gates_x MFMAs for token XV -> p[]  (one-hot as B-operand, n=row)
#define PRECOMP(XV) do {                                                       \
    const int xv_   = (XV);                                                    \
    const int hotw_ = 0x3F80 << ((xv_ & 1) << 4);                              \
    const int hoth_ = xv_ >> 1;                                                \
    A2U a2_;                                                                   \
    a2_.w.x = (hoth_ == kh + 0) ? hotw_ : 0;                                   \
    a2_.w.y = (hoth_ == kh + 1) ? hotw_ : 0;                                   \
    a2_.w.z = (hoth_ == kh + 2) ? hotw_ : 0;                                   \
    a2_.w.w = (hoth_ == kh + 3) ? hotw_ : 0;                                   \
    _Pragma("unroll")                                                          \
    for (int nt = 0; nt < 8; ++nt)                                             \
        p[nt] = __builtin_amdgcn_mfma_f32_16x16x32_bf16(b2f[nt], a2_.v, z, 0, 0, 0); \
} while (0)

// One timestep. On entry p[] = this step's gates_x, hb = h fragment (t>0).
#define SLOT(FIRST, LAST, XVN) do {                                            \
    f32x4 acc_[8];                                                             \
    if (FIRST) {                                                               \
        _Pragma("unroll")                                                      \
        for (int nt = 0; nt < 8; ++nt) acc_[nt] = p[nt];                       \
    } else {                                                                   \
        _Pragma("unroll")                                                      \
        for (int nt = 0; nt < 8; ++nt)                                         \
            acc_[nt] = __builtin_amdgcn_mfma_f32_16x16x32_bf16(b1f[nt], hb, p[nt], 0, 0, 0); \
    }                                                                          \
    /* ---- SoA pass 1: 32 independent exp2 ---- */                            \
    float ea_[8], ew_[8], eb_[8], ev_[8];                                      \
    _Pragma("unroll")                                                          \
    for (int k = 0; k < 8; ++k) {                                              \
        const int qq_ = k >> 2, r_ = k & 3;                                    \
        ea_[k] = ex2(acc_[qq_    ][r_]);   /* i */                             \
        ew_[k] = ex2(acc_[qq_ + 2][r_]);   /* f */                             \
        eb_[k] = ex2(acc_[qq_ + 4][r_]);   /* g (2x scale) */                  \
        ev_[k] = ex2(acc_[qq_ + 6][r_]);   /* o */                             \
    }                                                                          \
    /* ---- pass 2a: c-update, pairwise-fused rcp ---- */                      \
    float TP_[8], N_[8], dd_[8];                                               \
    _Pragma("unroll")                                                          \
    for (int k = 0; k < 8; ++k) {                                              \
        const float P_ = (1.0f + ea_[k]) * (1.0f + eb_[k]);                    \
        const float T_ = 1.0f + ew_[k];                                        \
        const float G_ = fmaf(2.88539008f, eb_[k], -2.88539008f);              \
        TP_[k] = T_ * P_;                                                      \
        N_[k]  = fmaf(d[k], P_, G_ * T_);                                      \
    }                                                                          \
    _Pragma("unroll")                                                          \
    for (int kp = 0; kp < 4; ++kp) {                                           \
        const int k0 = 2 * kp, k1 = 2 * kp + 1;                                \
        const float xr = rcpf_(TP_[k0] * TP_[k1]);                             \
        dd_[k0] = fminf(N_[k0] * xr * TP_[k1], 40.0f);                         \
        dd_[k1] = fminf(N_[k1] * xr * TP_[k0], 40.0f);                         \
        d[k0] = dd_[k0];                                                       \
        d[k1] = dd_[k1];                                                       \
    }                                                                          \
    /* ---- pass 2b: h, pairwise-fused rcp ---- */                             \
    float eu_[8], U_[8];                                                       \
    _Pragma("unroll")                                                          \
    for (int k = 0; k < 8; ++k) {                                              \
        eu_[k] = ex2(dd_[k]);                                                  \
        U_[k]  = (1.0f + ev_[k]) * (1.0f + eu_[k]);                            \
    }                                                                          \
    _Pragma("unroll")                                                          \
    for (int kp = 0; kp < 4; ++kp) {                                           \
        const int k0 = 2 * kp, k1 = 2 * kp + 1;                                \
        const float yr = rcpf_(U_[k0] * U_[k1]);                               \
        const float hv0 = (1.0f - eu_[k0]) * yr * U_[k1];                      \
        const float hv1 = (1.0f - eu_[k1]) * yr * U_[k0];                      \
        if (!(LAST)) {                                                         \
            hb[k0] = (__bf16)hv0;                                              \
            hb[k1] = (__bf16)hv1;                                              \
        } else {                                                               \
            fbuf[l15][kbase + k0] = hv0;                                       \
            fbuf[l15][kbase + k1] = hv1;                                       \
        }                                                                      \
    }                                                                          \
    if (!(LAST)) PRECOMP(XVN);   /* next-step gates_x */                       \
} while (0)

    // ---- prologue: tokens 0-3 and 4-7; gates_x for t=0 ----
    int4 q0 = *(const int4*)xrow;
    int4 xq = *(const int4*)(xrow + 4);
    PRECOMP(q0.x);

    // t = 0..3
    SLOT(true,  false, q0.y);
    SLOT(false, false, q0.z);
    SLOT(false, false, q0.w);
    SLOT(false, false, xq.x);

    // main: t = 4..123, 4 steps/iter; tokens prefetched one iteration ahead
    #pragma unroll 1
    for (int t = 4; t < 124; t += 4) {
        const int4 n = *(const int4*)(xrow + t + 4);
        SLOT(false, false, xq.y);   // t
        SLOT(false, false, xq.z);   // t+1
        SLOT(false, false, xq.w);   // t+2
        SLOT(false, false, n.x);    // t+3
        xq = n;
    }

    // tail: t = 124..127
    SLOT(false, false, xq.y);       // 124
    SLOT(false, false, xq.z);       // 125
    SLOT(false, false, xq.w);       // 126
    SLOT(false, true,  0);          // 127 -> fbuf (f32)

#undef SLOT
#undef PRECOMP

    __syncthreads();   // single wave: drains fbuf writes before cross-lane read

    // ---- FC epilogue: out[b] = h_last[b] @ fc_w^T + fc_b ----
    if (lane < 16) {
        float o0 = fc_b[0], o1 = fc_b[1];
        #pragma unroll
        for (int jj = 0; jj < HDIM; ++jj) {
            const float h = fbuf[lane][jj];
            o0 += fc_w[jj]        * h;
            o1 += fc_w[HDIM + jj] * h;
        }
        float2 res;
        res.x = o0; res.y = o1;
        *(float2*)&out[(row0 + lane) * 2] = res;
    }
}

extern "C" void kernel_launch(void* const* d_in, const int* in_sizes, int n_in,
                              void* d_out, int out_size, void* d_ws, size_t ws_size,
                              hipStream_t stream) {
    const int*   x    = (const int*)  d_in[0];
    const float* emb  = (const float*)d_in[1];
    const float* W_ih = (const float*)d_in[2];
    const float* W_hh = (const float*)d_in[3];
    const float* b_ih = (const float*)d_in[4];
    const float* b_hh = (const float*)d_in[5];
    const float* fc_w = (const float*)d_in[6];
    const float* fc_b = (const float*)d_in[7];
    float* out = (float*)d_out;

    const int B    = in_sizes[0] / TLEN;   // 16384
    const int nblk = B / 16;               // 1024 waves, 1 per SIMD chip-wide

    lstm_fused<<<nblk, 64, 0, stream>>>(x, emb, W_ih, W_hh, b_ih, b_hh, fc_w, fc_b, out);
}

// Round 18
// 102.314 us; speedup vs baseline: 1.0170x; 1.0000x over previous
//
#include <hip/hip_runtime.h>
#include <hip/hip_bf16.h>

typedef __bf16 bf16x8 __attribute__((ext_vector_type(8)));
typedef __bf16 bf16x4 __attribute__((ext_vector_type(4)));
typedef short  s16x4  __attribute__((ext_vector_type(4)));
typedef float  f32x4  __attribute__((ext_vector_type(4)));

#define VOCAB 24
#define EDIM  16
#define HDIM  32
#define TLEN  128

union A2U { int4 w; bf16x8 v; };
union H4U { bf16x4 h; s16x4 s; };

__device__ __forceinline__ float ex2(float x)  { return __builtin_amdgcn_exp2f(x); }
__device__ __forceinline__ float rcpf_(float x){ return __builtin_amdgcn_rcpf(x); }

// K=16 bf16 MFMA (gfx90a-era builtin, carried on gfx950; takes short4).
__device__ __forceinline__ f32x4 mfma_k16(bf16x4 a, bf16x4 b, f32x4 c) {
    H4U ua, ub; ua.h = a; ub.h = b;
    return __builtin_amdgcn_mfma_f32_16x16x16bf16_1k(ua.s, ub.s, c, 0, 0, 0);
}

// EXCHANGE-FREE wave-private design + SPLIT-K PIPELINING.
// Block = 1 wave = 16 batch rows. Swapped-operand MFMA: gates^T =
// mfma(A=W-frags, B=h^T/onehot^T), D[m=gatecol][n=row].
// Column permutation (simpler than R15's): tile nt (gate g=nt>>1, half=nt&1)
// covers gcol = g*32 + m + 16*(nt&1); lane (l15,hi) reads D[m=4hi+r][n=l15]
// -> gate g of hidden j = 4hi+r+16*(nt&1), batch row l15.
// Element k (k=0..7): j = 4hi+(k&3)+16*(k>>2); i=acc[k>>2], f=acc[2+(k>>2)],
// g=acc[4+(k>>2)], o=acc[6+(k>>2)] at reg r=k&3.
// SPLIT-K: h contribution = W_hi.h_hi + W_lo.h_lo via 2x8 K=16 MFMAs
// (16x16x16bf16_1k: A/B k = 4*(lane>>4)+i). Lane's low B-frag needs
// h[l15][4hi+i] = own hv_[0..3]; high needs h[l15][16+4hi+i] = own hv_[4..7].
// Slot: [8 hi-MFMAs (close step t)] -> GUPD-low -> [PRECOMP(t+1) K=32 +
// 8 lo-MFMAs for t+1 — off-chain filler] -> GUPD-high. The serial chain is
// halved; next step's low MFMA work issues under this step's GUPD-high.
// t=0 needs no special case: hbl=hbh=0 fragments contribute exactly 0.
// Activations: R16-verified fused-reciprocal pairwise form, 6 trans/element;
// B pre-scaled by -log2e (i,f,o) / -2log2e (g); d = -2log2e*c domain;
// dd clamped at +40 (exact tanh saturation).
__global__ __launch_bounds__(64) void lstm_fused(
    const int*   __restrict__ x,     // [B][128]
    const float* __restrict__ emb,   // [24][16]
    const float* __restrict__ W_ih,  // [128][16]
    const float* __restrict__ W_hh,  // [128][32]
    const float* __restrict__ b_ih,  // [128]
    const float* __restrict__ b_hh,  // [128]
    const float* __restrict__ fc_w,  // [2][32]
    const float* __restrict__ fc_b,  // [2]
    float*       __restrict__ out)   // [B][2]
{
    __shared__ __align__(16) float fbuf[16][33];   // final h (f32), FC only

    const int lane  = threadIdx.x;       // 0..63
    const int l15   = lane & 15;
    const int hi    = lane >> 4;         // 0..3
    const int kbase = hi * 8;            // K=32 vocab fragment base
    const int k4    = hi * 4;            // K=16 fragment base
    const int kh    = hi * 4;            // packed-word index base (one-hot)
    const int row0  = blockIdx.x * 16;

    // ---- A-fragments, pre-scaled, registers ----
    bf16x4 b1lo[8], b1hi[8];   // scale * W_hh[gcol][k], k=4hi+i / 16+4hi+i
    bf16x8 b2f[8];             // scale * (emb[v].W_ih[gcol] + b_ih + b_hh)
    #pragma unroll
    for (int nt = 0; nt < 8; ++nt) {
        const int g    = nt >> 1;
        const int gcol = g * 32 + l15 + 16 * (nt & 1);
        const float scale = (g == 2) ? -2.88539008f : -1.44269504f;
        const float* wrow = W_hh + gcol * HDIM;
        #pragma unroll
        for (int i = 0; i < 4; ++i) {
            b1lo[nt][i] = (__bf16)(scale * wrow[k4 + i]);
            b1hi[nt][i] = (__bf16)(scale * wrow[16 + k4 + i]);
        }
        const float bias = b_ih[gcol] + b_hh[gcol];
        const float* wi = W_ih + gcol * EDIM;
        #pragma unroll
        for (int i = 0; i < 8; ++i) {
            const int v = kbase + i;
            float s = 0.0f;
            if (v < VOCAB) {
                s = bias;
                #pragma unroll
                for (int e = 0; e < EDIM; ++e)
                    s += emb[v * EDIM + e] * wi[e];
            }
            b2f[nt][i] = (__bf16)(scale * s);
        }
    }

    float d[8];                          // d = -2*log2e * c  (scaled domain)
    #pragma unroll
    for (int q = 0; q < 8; ++q) d[q] = 0.0f;

    f32x4 p[8];                          // one-hot gates_x accumulators
    f32x4 accLo[8];                      // p + W_lo.h_lo (pipelined)
    bf16x4 hbl, hbh;                     // h B-fragments (own values)
    #pragma unroll
    for (int i = 0; i < 4; ++i) { hbl[i] = (__bf16)0.0f; hbh[i] = (__bf16)0.0f; }

    const f32x4 z = {0.f, 0.f, 0.f, 0.f};
    const int* xrow = x + (row0 + l15) * TLEN;   // tokens of batch row l15

// one-hot gates_x MFMAs for token XV -> p[]  (K=32, one-hot as B, n=row)
#define PRECOMP(XV) do {                                                       \
    const int xv_   = (XV);                                                    \
    const int hotw_ = 0x3F80 << ((xv_ & 1) << 4);                              \
    const int hoth_ = xv_ >> 1;                                                \
    A2U a2_;                                                                   \
    a2_.w.x = (hoth_ == kh + 0) ? hotw_ : 0;                                   \
    a2_.w.y = (hoth_ == kh + 1) ? hotw_ : 0;                                   \
    a2_.w.z = (hoth_ == kh + 2) ? hotw_ : 0;                                   \
    a2_.w.w = (hoth_ == kh + 3) ? hotw_ : 0;                                   \
    _Pragma("unroll")                                                          \
    for (int nt = 0; nt < 8; ++nt)                                             \
        p[nt] = __builtin_amdgcn_mfma_f32_16x16x32_bf16(b2f[nt], a2_.v, z, 0, 0, 0); \
} while (0)

// GUPD for half H (elements 4H..4H+3): R16 pairwise-fused activations.
#define GHALF(H, LAST) do {                                                    \
    float ea_[4], ew_[4], eb_[4], ev_[4];                                      \
    _Pragma("unroll")                                                          \
    for (int s = 0; s < 4; ++s) {                                              \
        ea_[s] = ex2(acc_[(H)    ][s]);   /* i */                              \
        ew_[s] = ex2(acc_[(H) + 2][s]);   /* f */                              \
        eb_[s] = ex2(acc_[(H) + 4][s]);   /* g (2x scale) */                   \
        ev_[s] = ex2(acc_[(H) + 6][s]);   /* o */                              \
    }                                                                          \
    float TP_[4], N_[4], dd_[4];                                               \
    _Pragma("unroll")                                                          \
    for (int s = 0; s < 4; ++s) {                                              \
        const float P_ = (1.0f + ea_[s]) * (1.0f + eb_[s]);                    \
        const float T_ = 1.0f + ew_[s];                                        \
        const float G_ = fmaf(2.88539008f, eb_[s], -2.88539008f);              \
        TP_[s] = T_ * P_;                                                      \
        N_[s]  = fmaf(d[4 * (H) + s], P_, G_ * T_);                            \
    }                                                                          \
    _Pragma("unroll")                                                          \
    for (int sp = 0; sp < 2; ++sp) {                                           \
        const int k0 = 2 * sp, k1 = 2 * sp + 1;                                \
        const float xr = rcpf_(TP_[k0] * TP_[k1]);                             \
        dd_[k0] = fminf(N_[k0] * xr * TP_[k1], 40.0f);                         \
        dd_[k1] = fminf(N_[k1] * xr * TP_[k0], 40.0f);                         \
        d[4 * (H) + k0] = dd_[k0];                                             \
        d[4 * (H) + k1] = dd_[k1];                                             \
    }                                                                          \
    float eu_[4], U_[4];                                                       \
    _Pragma("unroll")                                                          \
    for (int s = 0; s < 4; ++s) {                                              \
        eu_[s] = ex2(dd_[s]);                                                  \
        U_[s]  = (1.0f + ev_[s]) * (1.0f + eu_[s]);                            \
    }                                                                          \
    _Pragma("unroll")                                                          \
    for (int sp = 0; sp < 2; ++sp) {                                           \
        const int k0 = 2 * sp, k1 = 2 * sp + 1;                                \
        const float yr  = rcpf_(U_[k0] * U_[k1]);                              \
        const float hv0 = (1.0f - eu_[k0]) * yr * U_[k1];                      \
        const float hv1 = (1.0f - eu_[k1]) * yr * U_[k0];                      \
        if (!(LAST)) {                                                         \
            if (H) { hbh[k0] = (__bf16)hv0; hbh[k1] = (__bf16)hv1; }           \
            else   { hbl[k0] = (__bf16)hv0; hbl[k1] = (__bf16)hv1; }           \
        } else {                                                               \
            fbuf[l15][4 * hi + k0 + 16 * (H)] = hv0;                           \
            fbuf[l15][4 * hi + k1 + 16 * (H)] = hv1;                           \
        }                                                                      \
    }                                                                          \
} while (0)

// One timestep. Entry: accLo = gates_x(t) + W_lo.h_lo(t) [issued in t-1],
// hbh = h_hi(t-1). Exit (non-LAST): accLo = gates_x(t+1) + W_lo.h_lo(t),
// hbh = h_hi(t).
#define SLOT(LAST, XVN) do {                                                   \
    f32x4 acc_[8];                                                             \
    _Pragma("unroll")                                                          \
    for (int nt = 0; nt < 8; ++nt)                                             \
        acc_[nt] = mfma_k16(b1hi[nt], hbh, accLo[nt]);   /* close step t */    \
    GHALF(0, LAST);                                      /* -> hbl = h_lo(t) */\
    if (!(LAST)) {                                                             \
        PRECOMP(XVN);                                    /* gates_x(t+1) */    \
        _Pragma("unroll")                                                      \
        for (int nt = 0; nt < 8; ++nt)                                         \
            accLo[nt] = mfma_k16(b1lo[nt], hbl, p[nt]);  /* off-chain fill */  \
    }                                                                          \
    GHALF(1, LAST);                                      /* -> hbh = h_hi(t) */\
} while (0)

    // ---- prologue: tokens 0-3 and 4-7; accLo = gates_x(t=0) ----
    int4 q0 = *(const int4*)xrow;
    int4 xq = *(const int4*)(xrow + 4);
    PRECOMP(q0.x);
    #pragma unroll
    for (int nt = 0; nt < 8; ++nt) accLo[nt] = p[nt];

    // t = 0..3  (zero h-fragments make t=0 exact — no special case)
    SLOT(false, q0.y);
    SLOT(false, q0.z);
    SLOT(false, q0.w);
    SLOT(false, xq.x);

    // main: t = 4..123, 4 steps/iter; tokens prefetched one iteration ahead
    #pragma unroll 1
    for (int t = 4; t < 124; t += 4) {
        const int4 n = *(const int4*)(xrow + t + 4);
        SLOT(false, xq.y);   // t
        SLOT(false, xq.z);   // t+1
        SLOT(false, xq.w);   // t+2
        SLOT(false, n.x);    // t+3
        xq = n;
    }

    // tail: t = 124..127
    SLOT(false, xq.y);       // 124
    SLOT(false, xq.z);       // 125
    SLOT(false, xq.w);       // 126
    SLOT(true,  0);          // 127 -> fbuf (f32)

#undef SLOT
#undef GHALF
#undef PRECOMP

    __syncthreads();   // single wave: drains fbuf writes before cross-lane read

    // ---- FC epilogue: out[b] = h_last[b] @ fc_w^T + fc_b ----
    if (lane < 16) {
        float o0 = fc_b[0], o1 = fc_b[1];
        #pragma unroll
        for (int jj = 0; jj < HDIM; ++jj) {
            const float h = fbuf[lane][jj];
            o0 += fc_w[jj]        * h;
            o1 += fc_w[HDIM + jj] * h;
        }
        float2 res;
        res.x = o0; res.y = o1;
        *(float2*)&out[(row0 + lane) * 2] = res;
    }
}

extern "C" void kernel_launch(void* const* d_in, const int* in_sizes, int n_in,
                              void* d_out, int out_size, void* d_ws, size_t ws_size,
                              hipStream_t stream) {
    const int*   x    = (const int*)  d_in[0];
    const float* emb  = (const float*)d_in[1];
    const float* W_ih = (const float*)d_in[2];
    const float* W_hh = (const float*)d_in[3];
    const float* b_ih = (const float*)d_in[4];
    const float* b_hh = (const float*)d_in[5];
    const float* fc_w = (const float*)d_in[6];
    const float* fc_b = (const float*)d_in[7];
    float* out = (float*)d_out;

    const int B    = in_sizes[0] / TLEN;   // 16384
    const int nblk = B / 16;               // 1024 waves, 1 per SIMD chip-wide

    lstm_fused<<<nblk, 64, 0, stream>>>(x, emb, W_ih, W_hh, b_ih, b_hh, fc_w, fc_b, out);
}